// Round 3
// baseline (811.651 us; speedup 1.0000x reference)
//
#include <hip/hip_runtime.h>
#include <math.h>

typedef __attribute__((ext_vector_type(8))) short short8;
typedef __attribute__((ext_vector_type(4))) float f32x4;

namespace {
constexpr int B_ = 8;
constexpr int N_ = 2048;
constexpr int D_ = 1024;
constexpr float NEGV = -1.0e9f;
}

__device__ __forceinline__ unsigned short f2bf(float x) {
    union { float f; unsigned u; } v; v.f = x;
    unsigned u = v.u + 0x7fffu + ((v.u >> 16) & 1u);
    return (unsigned short)(u >> 16);
}

// ---------------------------------------------------------------------------
// Per-batch valid lengths from the prefix mask (uint8 or int32 layout).
// ---------------------------------------------------------------------------
__global__ __launch_bounds__(256)
void k_lengths(const unsigned char* __restrict__ mask, int* __restrict__ L)
{
    const int b = blockIdx.x;
    const int t = threadIdx.x;
    const bool u8 = (mask[1] != 0);
    int cnt = 0;
    if (u8) {
        for (int n = t; n < N_; n += 256)
            cnt += (mask[(size_t)b * N_ + n] != 0) ? 1 : 0;
    } else {
        const int* mi = (const int*)mask;
        for (int n = t; n < N_; n += 256)
            cnt += (mi[(size_t)b * N_ + n] != 0) ? 1 : 0;
    }
    __shared__ int red[256];
    red[t] = cnt;
    __syncthreads();
    for (int s = 128; s > 0; s >>= 1) {
        if (t < s) red[t] += red[t + s];
        __syncthreads();
    }
    if (t == 0) L[b] = red[0];
}

// ---------------------------------------------------------------------------
// f32 -> bf16 conversion (with optional scale), 1 float4 per thread.
// ---------------------------------------------------------------------------
__global__ __launch_bounds__(256)
void convert_bf16(const float* __restrict__ in, unsigned short* __restrict__ out,
                  int n4, float alpha)
{
    const int i = blockIdx.x * 256 + threadIdx.x;
    if (i >= n4) return;
    const float4 v = ((const float4*)in)[i];
    ushort4 o;
    o.x = f2bf(v.x * alpha); o.y = f2bf(v.y * alpha);
    o.z = f2bf(v.z * alpha); o.w = f2bf(v.w * alpha);
    ((ushort4*)out)[i] = o;
}

// ---------------------------------------------------------------------------
// 256x256 8-phase bf16 NT-GEMM (C[m][n] = sum_k A[m][k]*B[n][k]).
//
// 512 threads = 8 waves (2 Mrow x 4 Ncol), per-wave 128x64 output,
// 16x16x32 MFMA, BK=64, double-buffered 128 KiB LDS, counted vmcnt.
//
// LDS rows are 128 B (8 x 16B segs). Seg swizzle: phys = logical ^ ((row>>1)&7).
// Staging pre-swizzles the GLOBAL source seg so the LDS dest stays linear
// (global_load_lds constraint).
//
// Schedule per K-tile (4 barrier-separated phases; tile T in dbuf d=T&1):
//  q1: dsread T.Bn23+T.Am45 (8) | stage (T+1).Bh0 -> d^1 | BAR lgkm0 MFMA(m0-3 x n01)  BAR
//  q2: dsread T.Am67 (4)        | stage (T+1).Bh1 -> d^1 | BAR lgkm0 MFMA(m0-3 x n23)  BAR
//  q3:                          | stage (T+2).Ah0 -> d   | vmcnt(2) BAR lgkm0 MFMA(m4-7 x n01) BAR
//  q4: dsread (T+1).Am0-3+Bn01  | stage (T+2).Ah1 -> d   | BAR lgkm0 MFMA(m4-7 x n23)  BAR
//
// vmcnt ledger at q3 (steady state, oldest first): (T+1).Ah0, Ah1 [q3/q4 of
// T-1], (T+1).Bh0 [q1], (T+1).Bh1 [q2], (T+2).Ah0 [q3] = 10 outstanding;
// vmcnt(2) drains through (T+1).Bh1 -> all of tile T+1 landed before the q3
// mid-barrier, so q4/q1/q2 reads of T+1 are safe. TAIL FIX (round-2 bug):
// when kt+2 >= NT the q3 stage is absent -> only 8 outstanding, vmcnt(2)
// would leave (T+1).Bh1 in flight; use vmcnt(0) there instead.
//
// OUT_MODE: 0 = f32, 1 = bf16, 2 = f32 with prefix mask (logits; tiles fully
// outside Lb x Lb write NEGV and exit before any barrier).
// MFAST: within-XCD-chunk ordering walks M fastest (B-panel stays L2-hot).
// ---------------------------------------------------------------------------
template <int OUT_MODE, bool MFAST>
__global__ __launch_bounds__(512, 2)
void gemm_nt_256(const unsigned short* __restrict__ A, int lda, long strideA,
                 const unsigned short* __restrict__ Bm, int ldb, long strideB,
                 void* __restrict__ Cout, int ldc, long strideC,
                 int K, const int* __restrict__ Lp)
{
    __shared__ __attribute__((aligned(16))) short As[2][16384];
    __shared__ __attribute__((aligned(16))) short Bs[2][16384];

    const int tid  = threadIdx.x;
    const int lane = tid & 63;
    const int wave = tid >> 6;
    const int wr   = wave >> 2;   // 0..1
    const int wc   = wave & 3;    // 0..3

    // ---- XCD-aware bijective block swizzle ----
    const unsigned gx   = gridDim.x;
    const unsigned gy   = gridDim.y;
    const unsigned gxy  = gx * gy;
    const unsigned total = gxy * gridDim.z;
    const unsigned orig = blockIdx.x + gx * blockIdx.y + gxy * blockIdx.z;
    unsigned wg = orig;
    if ((total & 7u) == 0u)
        wg = (orig & 7u) * (total >> 3) + (orig >> 3);
    const unsigned bz  = wg / gxy;
    const unsigned rem = wg - bz * gxy;
    unsigned byy, bxx;
    if (MFAST) { byy = rem % gy; bxx = rem / gy; }
    else       { byy = rem / gx; bxx = rem % gx; }

    const int b  = (int)bz;
    const int m0 = (int)byy * 256;
    const int n0 = (int)bxx * 256;

    int Lb = 0;
    if (OUT_MODE == 2) {
        Lb = Lp[b];
        if (m0 >= Lb || n0 >= Lb) {
            // whole tile is masked: write NEGV, skip all compute (no barriers hit)
            float* C = (float*)Cout + (long)b * strideC;
            const float4 nv = make_float4(NEGV, NEGV, NEGV, NEGV);
            const int rl = tid >> 6;          // 0..7
            const int c4 = (tid & 63) * 4;    // 0..252
#pragma unroll
            for (int l = 0; l < 32; ++l)
                *(float4*)(C + (long)(m0 + l * 8 + rl) * ldc + n0 + c4) = nv;
            return;
        }
    }

    const unsigned short* Ab = A  + (long)b * strideA;
    const unsigned short* Bb = Bm + (long)b * strideB;

    // staging: per global_load_lds issue, 512 threads cover 64 rows x 128 B.
    // chunk = tid: row = tid>>3, phys seg = tid&7; pre-swizzled global seg:
    const int srow = tid >> 3;
    const int sseg = ((tid & 7) ^ ((tid >> 4) & 7)) * 8;   // shorts
    const unsigned short* gA = Ab + (long)(m0 + srow) * lda + sseg;
    const unsigned short* gB = Bb + (long)(n0 + srow) * ldb + sseg;
    const int ldst = (tid & ~63) * 8;   // wave-uniform LDS chunk base (shorts)

    // fragment read addressing: row = base + r, phys seg = (ks*4+q) ^ ((r>>1)&7)
    const int q  = lane >> 4, r = lane & 15;
    const int h8 = (r >> 1) & 7;
    const int arb = (wr * 128 + r) * 64;
    const int brb = (wc * 64 + r) * 64;
    int pk[2];
    pk[0] = (q ^ h8) * 8;
    pk[1] = pk[0] ^ 32;   // seg +4

    const int NT = K >> 6;   // K-tiles of 64 (K % 128 == 0 for all launches)

    short8 aF[8][2];
    short8 bF[4][2];
    f32x4  acc[8][4] = {};

#define STAGE_A2(dd, hh, kt) do {                                              \
    __builtin_amdgcn_global_load_lds(                                          \
        (const __attribute__((address_space(1))) void*)(gA + (long)((hh)*128)*lda + (long)(kt)*64),      \
        (__attribute__((address_space(3))) void*)(&As[dd][(hh)*8192 + ldst]), 16, 0, 0);                 \
    __builtin_amdgcn_global_load_lds(                                          \
        (const __attribute__((address_space(1))) void*)(gA + (long)((hh)*128 + 64)*lda + (long)(kt)*64), \
        (__attribute__((address_space(3))) void*)(&As[dd][(hh)*8192 + 4096 + ldst]), 16, 0, 0);          \
} while (0)

#define STAGE_B2(dd, hh, kt) do {                                              \
    __builtin_amdgcn_global_load_lds(                                          \
        (const __attribute__((address_space(1))) void*)(gB + (long)((hh)*128)*ldb + (long)(kt)*64),      \
        (__attribute__((address_space(3))) void*)(&Bs[dd][(hh)*8192 + ldst]), 16, 0, 0);                 \
    __builtin_amdgcn_global_load_lds(                                          \
        (const __attribute__((address_space(1))) void*)(gB + (long)((hh)*128 + 64)*ldb + (long)(kt)*64), \
        (__attribute__((address_space(3))) void*)(&Bs[dd][(hh)*8192 + 4096 + ldst]), 16, 0, 0);          \
} while (0)

#define LDA_F(dd, mrep, ks) aF[mrep][ks] = *(const short8*)&As[dd][arb + (mrep)*1024 + pk[ks]]
#define LDB_F(dd, nrep, ks) bF[nrep][ks] = *(const short8*)&Bs[dd][brb + (nrep)*1024 + pk[ks]]

#define BARX __builtin_amdgcn_s_barrier()
#define WAIT_LGKM0 do { asm volatile("s_waitcnt lgkmcnt(0)" ::: "memory"); \
                        __builtin_amdgcn_sched_barrier(0); } while (0)
#define WAIT_VM0   do { asm volatile("s_waitcnt vmcnt(0)"   ::: "memory"); \
                        __builtin_amdgcn_sched_barrier(0); } while (0)
#define WAIT_VM2   do { asm volatile("s_waitcnt vmcnt(2)"   ::: "memory"); \
                        __builtin_amdgcn_sched_barrier(0); } while (0)
#define WAIT_VM4   do { asm volatile("s_waitcnt vmcnt(4)"   ::: "memory"); \
                        __builtin_amdgcn_sched_barrier(0); } while (0)

#define MFMA_Q(mh, nh) do {                                                    \
    __builtin_amdgcn_s_setprio(1);                                             \
    _Pragma("unroll") for (int mr = 0; mr < 4; ++mr)                           \
    _Pragma("unroll") for (int nr = 0; nr < 2; ++nr)                           \
    _Pragma("unroll") for (int ks = 0; ks < 2; ++ks)                           \
        acc[(mh)*4+mr][(nh)*2+nr] = __builtin_amdgcn_mfma_f32_16x16x32_bf16(   \
            aF[(mh)*4+mr][ks], bF[(nh)*2+nr][ks], acc[(mh)*4+mr][(nh)*2+nr], 0, 0, 0); \
    __builtin_amdgcn_s_setprio(0);                                             \
} while (0)

#define TILE_STEP(d, kt) do {                                                  \
    /* q1 */                                                                   \
    LDB_F(d, 2, 0); LDB_F(d, 2, 1); LDB_F(d, 3, 0); LDB_F(d, 3, 1);            \
    LDA_F(d, 4, 0); LDA_F(d, 4, 1); LDA_F(d, 5, 0); LDA_F(d, 5, 1);            \
    if ((kt) + 1 < NT) STAGE_B2((d) ^ 1, 0, (kt) + 1);                         \
    BARX; WAIT_LGKM0; MFMA_Q(0, 0); BARX;                                      \
    /* q2 */                                                                   \
    LDA_F(d, 6, 0); LDA_F(d, 6, 1); LDA_F(d, 7, 0); LDA_F(d, 7, 1);            \
    if ((kt) + 1 < NT) STAGE_B2((d) ^ 1, 1, (kt) + 1);                         \
    BARX; WAIT_LGKM0; MFMA_Q(0, 1); BARX;                                      \
    /* q3 — tail-aware counted wait: with the (T+2).Ah0 stage issued,          \
       vmcnt(2) drains through (T+1).Bh1; without it, must drain to 0. */      \
    if ((kt) + 2 < NT) { STAGE_A2(d, 0, (kt) + 2); WAIT_VM2; }                 \
    else               { WAIT_VM0; }                                           \
    BARX; WAIT_LGKM0; MFMA_Q(1, 0); BARX;                                      \
    /* q4 */                                                                   \
    if ((kt) + 1 < NT) {                                                       \
        LDA_F((d) ^ 1, 0, 0); LDA_F((d) ^ 1, 0, 1);                            \
        LDA_F((d) ^ 1, 1, 0); LDA_F((d) ^ 1, 1, 1);                            \
        LDA_F((d) ^ 1, 2, 0); LDA_F((d) ^ 1, 2, 1);                            \
        LDA_F((d) ^ 1, 3, 0); LDA_F((d) ^ 1, 3, 1);                            \
        LDB_F((d) ^ 1, 0, 0); LDB_F((d) ^ 1, 0, 1);                            \
        LDB_F((d) ^ 1, 1, 0); LDB_F((d) ^ 1, 1, 1);                            \
    }                                                                          \
    if ((kt) + 2 < NT) STAGE_A2(d, 1, (kt) + 2);                               \
    BARX; WAIT_LGKM0; MFMA_Q(1, 1); BARX;                                      \
} while (0)

    // prologue: tile0 A+B -> dbuf0, tile1 A -> dbuf1; wait tile0 landed.
    STAGE_A2(0, 0, 0); STAGE_A2(0, 1, 0);
    STAGE_B2(0, 0, 0); STAGE_B2(0, 1, 0);
    STAGE_A2(1, 0, 1); STAGE_A2(1, 1, 1);
    WAIT_VM4; BARX;
    // pre-read tile0's Q1 fragment set
    LDA_F(0, 0, 0); LDA_F(0, 0, 1); LDA_F(0, 1, 0); LDA_F(0, 1, 1);
    LDA_F(0, 2, 0); LDA_F(0, 2, 1); LDA_F(0, 3, 0); LDA_F(0, 3, 1);
    LDB_F(0, 0, 0); LDB_F(0, 0, 1); LDB_F(0, 1, 0); LDB_F(0, 1, 1);

    for (int kt = 0; kt < NT; kt += 2) {
        TILE_STEP(0, kt);
        TILE_STEP(1, kt + 1);
    }

#undef STAGE_A2
#undef STAGE_B2
#undef LDA_F
#undef LDB_F
#undef BARX
#undef WAIT_LGKM0
#undef WAIT_VM0
#undef WAIT_VM2
#undef WAIT_VM4
#undef MFMA_Q
#undef TILE_STEP

    // epilogue: C/D layout col = lane&15 (=r), row = (lane>>4)*4 + reg (=q*4+rr)
    const int rbase = m0 + wr * 128;
    const int cbase = n0 + wc * 64;
    if (OUT_MODE == 1) {
        unsigned short* C = (unsigned short*)Cout + (long)b * strideC;
#pragma unroll
        for (int mt = 0; mt < 8; ++mt)
#pragma unroll
            for (int nt = 0; nt < 4; ++nt)
#pragma unroll
                for (int rr = 0; rr < 4; ++rr) {
                    const int grow = rbase + mt * 16 + q * 4 + rr;
                    const int gcol = cbase + nt * 16 + r;
                    C[(long)grow * ldc + gcol] = f2bf(acc[mt][nt][rr]);
                }
    } else if (OUT_MODE == 0) {
        float* C = (float*)Cout + (long)b * strideC;
#pragma unroll
        for (int mt = 0; mt < 8; ++mt)
#pragma unroll
            for (int nt = 0; nt < 4; ++nt)
#pragma unroll
                for (int rr = 0; rr < 4; ++rr) {
                    const int grow = rbase + mt * 16 + q * 4 + rr;
                    const int gcol = cbase + nt * 16 + r;
                    C[(long)grow * ldc + gcol] = acc[mt][nt][rr];
                }
    } else {
        float* C = (float*)Cout + (long)b * strideC;
#pragma unroll
        for (int mt = 0; mt < 8; ++mt)
#pragma unroll
            for (int nt = 0; nt < 4; ++nt)
#pragma unroll
                for (int rr = 0; rr < 4; ++rr) {
                    const int grow = rbase + mt * 16 + q * 4 + rr;
                    const int gcol = cbase + nt * 16 + r;
                    const float val = (grow < Lb && gcol < Lb) ? acc[mt][nt][rr] : NEGV;
                    C[(long)grow * ldc + gcol] = val;
                }
    }
}

// ---------------------------------------------------------------------------
// In-place row softmax over last dim (N_=2048). One block per row.
// ---------------------------------------------------------------------------
__global__ __launch_bounds__(256)
void softmax_rows(float* __restrict__ Att)
{
    const size_t row = blockIdx.x;
    float* p = Att + row * (size_t)N_;
    const int t = threadIdx.x;

    float4 v0 = *(float4*)(p + t * 4);
    float4 v1 = *(float4*)(p + 1024 + t * 4);

    float mx = fmaxf(fmaxf(fmaxf(v0.x, v0.y), fmaxf(v0.z, v0.w)),
                     fmaxf(fmaxf(v1.x, v1.y), fmaxf(v1.z, v1.w)));
#pragma unroll
    for (int o = 32; o > 0; o >>= 1) mx = fmaxf(mx, __shfl_xor(mx, o, 64));

    __shared__ float red[8];
    const int wv = t >> 6;
    if ((t & 63) == 0) red[wv] = mx;
    __syncthreads();
    mx = fmaxf(fmaxf(red[0], red[1]), fmaxf(red[2], red[3]));

    float e[8];
    e[0] = expf(v0.x - mx); e[1] = expf(v0.y - mx);
    e[2] = expf(v0.z - mx); e[3] = expf(v0.w - mx);
    e[4] = expf(v1.x - mx); e[5] = expf(v1.y - mx);
    e[6] = expf(v1.z - mx); e[7] = expf(v1.w - mx);
    float s = ((e[0] + e[1]) + (e[2] + e[3])) + ((e[4] + e[5]) + (e[6] + e[7]));
#pragma unroll
    for (int o = 32; o > 0; o >>= 1) s += __shfl_xor(s, o, 64);
    if ((t & 63) == 0) red[4 + wv] = s;
    __syncthreads();
    const float inv = 1.0f / (red[4] + red[5] + red[6] + red[7]);

    *(float4*)(p + t * 4)        = make_float4(e[0] * inv, e[1] * inv, e[2] * inv, e[3] * inv);
    *(float4*)(p + 1024 + t * 4) = make_float4(e[4] * inv, e[5] * inv, e[6] * inv, e[7] * inv);
}

// ---------------------------------------------------------------------------
// att f32 [b][j][i] -> attT bf16 [b][i][j], 64x64 LDS tile transpose.
// ---------------------------------------------------------------------------
__global__ __launch_bounds__(256)
void transpose_att_bf16(const float* __restrict__ att, unsigned short* __restrict__ attT)
{
    __shared__ float tile[64][65];
    const int b  = blockIdx.z;
    const int j0 = blockIdx.y * 64;
    const int i0 = blockIdx.x * 64;
    const float* src = att + (long)b * N_ * N_;
    unsigned short* dst = attT + (long)b * N_ * N_;
    const int t = threadIdx.x;
#pragma unroll
    for (int l = 0; l < 4; ++l) {
        const int idx = t + l * 256;
        const int jj = idx >> 4;
        const int i4 = (idx & 15) * 4;
        const float4 v = *(const float4*)(src + (long)(j0 + jj) * N_ + i0 + i4);
        tile[i4 + 0][jj] = v.x;
        tile[i4 + 1][jj] = v.y;
        tile[i4 + 2][jj] = v.z;
        tile[i4 + 3][jj] = v.w;
    }
    __syncthreads();
#pragma unroll
    for (int l = 0; l < 4; ++l) {
        const int idx = t + l * 256;
        const int ii = idx >> 4;
        const int j4 = (idx & 15) * 4;
        ushort4 o;
        o.x = f2bf(tile[ii][j4 + 0]);
        o.y = f2bf(tile[ii][j4 + 1]);
        o.z = f2bf(tile[ii][j4 + 2]);
        o.w = f2bf(tile[ii][j4 + 3]);
        *(ushort4*)(dst + (long)(i0 + ii) * N_ + j0 + j4) = o;
    }
}

// ---------------------------------------------------------------------------
// V slice of QKV [16384 tokens][3072] (cols 2048..3071) -> VT bf16 [1024][16384]
// ---------------------------------------------------------------------------
__global__ __launch_bounds__(256)
void transpose_v_bf16(const unsigned short* __restrict__ qkv, unsigned short* __restrict__ vt)
{
    __shared__ unsigned short tile[64][68];
    const int j0 = blockIdx.x * 64;
    const int d0 = blockIdx.y * 64;
    const int t = threadIdx.x;
#pragma unroll
    for (int l = 0; l < 4; ++l) {
        const int idx = t + l * 256;
        const int jj = idx >> 4;
        const int d4 = (idx & 15) * 4;
        const ushort4 v = *(const ushort4*)(qkv + (long)(j0 + jj) * 3072 + 2048 + d0 + d4);
        tile[d4 + 0][jj] = v.x;
        tile[d4 + 1][jj] = v.y;
        tile[d4 + 2][jj] = v.z;
        tile[d4 + 3][jj] = v.w;
    }
    __syncthreads();
#pragma unroll
    for (int l = 0; l < 4; ++l) {
        const int idx = t + l * 256;
        const int dd = idx >> 4;
        const int j4 = (idx & 15) * 4;
        ushort4 o;
        o.x = tile[dd][j4 + 0];
        o.y = tile[dd][j4 + 1];
        o.z = tile[dd][j4 + 2];
        o.w = tile[dd][j4 + 3];
        *(ushort4*)(vt + (long)(d0 + dd) * 16384 + j0 + j4) = o;
    }
}

// ---------------------------------------------------------------------------
extern "C" void kernel_launch(void* const* d_in, const int* in_sizes, int n_in,
                              void* d_out, int out_size, void* d_ws, size_t ws_size,
                              hipStream_t stream)
{
    const float* x  = (const float*)d_in[0];
    const unsigned char* mask = (const unsigned char*)d_in[1];
    const float* Wq = (const float*)d_in[2];
    const float* Wk = (const float*)d_in[3];
    const float* Wv = (const float*)d_in[4];
    const float* Wo = (const float*)d_in[5];

    float* y   = (float*)d_out;                          // [B,N,D] f32
    float* att = (float*)d_out + (size_t)B_ * N_ * D_;   // [B,N,N] f32

    char* ws = (char*)d_ws;
    int* L = (int*)ws;
    unsigned short* Wqkvb = (unsigned short*)(ws + 256); // [3072,1024] (Q|K|V rows)
    unsigned short* Wob   = Wqkvb + 3145728;             // [1024,1024]
    unsigned short* xb    = Wob + 1048576;               // [16384,1024]
    unsigned short* QKVb  = xb + 16777216;               // [16384,3072]
    unsigned short* VT    = QKVb + 50331648;             // [1024,16384]
    unsigned short* attT  = QKVb;                        // [B,N,N] bf16 (reuses QKV)
    unsigned short* ctx   = xb;                          // [16384,1024] bf16 (reuses xb)

    const dim3 blk(256);
    const dim3 blk512(512);
    const long NN = (long)N_ * N_;
    const long ND = (long)N_ * D_;
    const long NQ = (long)N_ * 3072;

    k_lengths<<<dim3(B_), blk, 0, stream>>>(mask, L);

    convert_bf16<<<dim3(16384), blk, 0, stream>>>(x,  xb,  4194304, 1.0f);
    convert_bf16<<<dim3(1024),  blk, 0, stream>>>(Wq, Wqkvb,           262144, 0.06f);
    convert_bf16<<<dim3(1024),  blk, 0, stream>>>(Wk, Wqkvb + 1048576, 262144, 1.0f);
    convert_bf16<<<dim3(1024),  blk, 0, stream>>>(Wv, Wqkvb + 2097152, 262144, 1.0f);
    convert_bf16<<<dim3(1024),  blk, 0, stream>>>(Wo, Wob,             262144, 1.0f);

    // Fused QKV = x @ [Wq*0.06 | Wk | Wv]^T -> [16384, 3072] bf16
    gemm_nt_256<1, true><<<dim3(12, 64, 1), blk512, 0, stream>>>(
        xb, D_, 0, Wqkvb, D_, 0, QKVb, 3072, 0, D_, nullptr);

    // VT[d][b*N+j] = V[b*N+j][d]
    transpose_v_bf16<<<dim3(256, 16), blk, 0, stream>>>(QKVb, VT);

    // logits = Q K^T with prefix mask (f32 out into att region)
    gemm_nt_256<2, false><<<dim3(8, 8, B_), blk512, 0, stream>>>(
        QKVb, 3072, NQ, QKVb + 1024, 3072, NQ, att, N_, NN, D_, L);

    softmax_rows<<<dim3(B_ * N_), blk, 0, stream>>>(att);

    // attT bf16 (reuses QKV space; Q/K/V all consumed by now)
    transpose_att_bf16<<<dim3(32, 32, B_), blk, 0, stream>>>(att, attT);

    // ctx[b][i][d] = sum_j attT[b][i][j] * VT[d][b*N + j]
    gemm_nt_256<1, true><<<dim3(4, 8, B_), blk512, 0, stream>>>(
        attT, N_, NN, VT, B_ * N_, N_, ctx, D_, ND, N_, nullptr);

    // y = ctx Wo^T (f32 out)
    gemm_nt_256<0, false><<<dim3(4, 64, 1), blk512, 0, stream>>>(
        ctx, D_, 0, Wob, D_, 0, y, D_, 0, D_, nullptr);
}

// Round 4
// 633.257 us; speedup vs baseline: 1.2817x; 1.2817x over previous
//
#include <hip/hip_runtime.h>
#include <math.h>

typedef __attribute__((ext_vector_type(8))) short short8;
typedef __attribute__((ext_vector_type(4))) float f32x4;

namespace {
constexpr int B_ = 8;
constexpr int N_ = 2048;
constexpr int D_ = 1024;
constexpr float NEGV = -1.0e9f;
}

__device__ __forceinline__ unsigned short f2bf(float x) {
    union { float f; unsigned u; } v; v.f = x;
    unsigned u = v.u + 0x7fffu + ((v.u >> 16) & 1u);
    return (unsigned short)(u >> 16);
}

// ---------------------------------------------------------------------------
// Per-batch valid lengths from the prefix mask (uint8 or int32 layout).
// ---------------------------------------------------------------------------
__global__ __launch_bounds__(256)
void k_lengths(const unsigned char* __restrict__ mask, int* __restrict__ L)
{
    const int b = blockIdx.x;
    const int t = threadIdx.x;
    const bool u8 = (mask[1] != 0);
    int cnt = 0;
    if (u8) {
        for (int n = t; n < N_; n += 256)
            cnt += (mask[(size_t)b * N_ + n] != 0) ? 1 : 0;
    } else {
        const int* mi = (const int*)mask;
        for (int n = t; n < N_; n += 256)
            cnt += (mi[(size_t)b * N_ + n] != 0) ? 1 : 0;
    }
    __shared__ int red[256];
    red[t] = cnt;
    __syncthreads();
    for (int s = 128; s > 0; s >>= 1) {
        if (t < s) red[t] += red[t + s];
        __syncthreads();
    }
    if (t == 0) L[b] = red[0];
}

// ---------------------------------------------------------------------------
// f32 -> bf16 conversion (with optional scale), 1 float4 per thread.
// ---------------------------------------------------------------------------
__global__ __launch_bounds__(256)
void convert_bf16(const float* __restrict__ in, unsigned short* __restrict__ out,
                  int n4, float alpha)
{
    const int i = blockIdx.x * 256 + threadIdx.x;
    if (i >= n4) return;
    const float4 v = ((const float4*)in)[i];
    ushort4 o;
    o.x = f2bf(v.x * alpha); o.y = f2bf(v.y * alpha);
    o.z = f2bf(v.z * alpha); o.w = f2bf(v.w * alpha);
    ((ushort4*)out)[i] = o;
}

// ---------------------------------------------------------------------------
// 256x256 pipelined bf16 NT-GEMM (C[m][n] = sum_k A[m][k]*B[n][k]).
//
// 512 threads = 8 waves (2 Mrow x 4 Ncol), per-wave 128x64 output,
// 16x16x32 MFMA, BK=32, double-buffered 64 KiB LDS, counted vmcnt.
//
// REGISTER-LEAN redesign of the round-3 kernel, which spilled: VGPR=128
// (= 256 unified cap - 128 AGPR acc) + WRITE_SIZE 3.4x output = scratch
// traffic. Here each phase's MFMA consumes fragments ds_read in the SAME
// phase: live frags = aQ[8](32) + bQ[4](16) = 48 VGPR, total ~200 < 256.
//
// LDS rows are 64 B (4 x 16B segs). Seg swizzle: phys = logical ^ ((row>>1)&3)
// -> quarter-wave ds_read_b128 lands 2-way on banks (free, m136). Staging
// pre-swizzles the GLOBAL source seg; LDS dest stays linear (gload_lds rule).
//
// Per K-tile T (dbuf d=T&1), 2 phases:
//  P1: dsread A all-mreps (8) + B n01 (2) | stage (T+1).B -> d^1
//      | BAR lgkm0 MFMA(8m x n01) BAR
//  P2: dsread B n23 (2) | stage (T+2).A -> d + vmcnt(2)
//      | BAR lgkm0 MFMA(8m x n23) BAR
// Ledger at P2 wait (oldest first): (T+1).A x2 [P2 of T-1], (T+1).B x2 [P1],
// (T+2).A x2 [P2] = 6; vmcnt(2) drains all of T+1, leaves (T+2).A in flight
// across the tile boundary. Tails: kt+2>=NT -> vmcnt(0).
// WAR safety: stage into a region only after the phase-barrier that follows
// the lgkm0 draining the last read of that region (audited per phase).
//
// OUT_MODE: 0 = f32, 1 = bf16, 2 = f32 with prefix mask (logits):
//   m0 >= Lb -> return with NO writes (softmax writes those rows whole);
//   n0 >= Lb -> NEGV fill, no compute.
// XCD swizzle: bijective chunking, n-fastest within chunk (B-panel L2-hot).
// ---------------------------------------------------------------------------
template <int OUT_MODE>
__global__ __launch_bounds__(512, 2)
void gemm_nt_256(const unsigned short* __restrict__ A, int lda, long strideA,
                 const unsigned short* __restrict__ Bm, int ldb, long strideB,
                 void* __restrict__ Cout, int ldc, long strideC,
                 int K, const int* __restrict__ Lp)
{
    __shared__ __attribute__((aligned(16))) short As[2][8192];
    __shared__ __attribute__((aligned(16))) short Bs[2][8192];

    const int tid  = threadIdx.x;
    const int lane = tid & 63;
    const int wave = tid >> 6;
    const int wr   = wave >> 2;   // 0..1
    const int wc   = wave & 3;    // 0..3

    // ---- XCD-aware bijective block swizzle (n-fastest within chunk) ----
    const unsigned gx   = gridDim.x;
    const unsigned gxy  = gx * gridDim.y;
    const unsigned total = gxy * gridDim.z;
    const unsigned orig = blockIdx.x + gx * blockIdx.y + gxy * blockIdx.z;
    unsigned wg = orig;
    if ((total & 7u) == 0u)
        wg = (orig & 7u) * (total >> 3) + (orig >> 3);
    const unsigned bz  = wg / gxy;
    const unsigned rem = wg - bz * gxy;
    const unsigned byy = rem / gx;
    const unsigned bxx = rem - byy * gx;

    const int b  = (int)bz;
    const int m0 = (int)byy * 256;
    const int n0 = (int)bxx * 256;

    int Lb = 0;
    if (OUT_MODE == 2) {
        Lb = Lp[b];
        if (m0 >= Lb) return;   // softmax writes these rows entirely (const)
        if (n0 >= Lb) {
            // masked columns of valid rows: NEGV fill, no compute
            float* C = (float*)Cout + (long)b * strideC;
            const float4 nv = make_float4(NEGV, NEGV, NEGV, NEGV);
            const int rl = tid >> 6;          // 0..7
            const int c4 = (tid & 63) * 4;    // 0..252
#pragma unroll
            for (int l = 0; l < 32; ++l)
                *(float4*)(C + (long)(m0 + l * 8 + rl) * ldc + n0 + c4) = nv;
            return;
        }
    }

    const unsigned short* Ab = A  + (long)b * strideA;
    const unsigned short* Bb = Bm + (long)b * strideB;

    // staging: one gload_lds issue covers 128 rows x 64 B (512 thr x 16 B).
    // chunk = tid: row = tid>>2, phys seg = tid&3; pre-swizzled global seg:
    const int srow = tid >> 2;                               // 0..127
    const int sseg = ((tid & 3) ^ ((tid >> 3) & 3)) * 8;     // shorts
    const unsigned short* gA = Ab + (long)(m0 + srow) * lda + sseg;
    const unsigned short* gB = Bb + (long)(n0 + srow) * ldb + sseg;
    const int ldst = (tid & ~63) * 8;   // wave-uniform LDS chunk base (shorts)

    // fragment reads: row = base + r, phys seg = q ^ ((r>>1)&3)
    const int q  = lane >> 4, r = lane & 15;
    const int arb = (wr * 128 + r) * 32;
    const int brb = (wc * 64 + r) * 32;
    const int pk  = (q ^ ((r >> 1) & 3)) * 8;

    const int NT = K >> 5;   // K-tiles of 32 (all launches: K mult of 64)

    short8 aQ[8];
    short8 bQ[4];
    f32x4  acc[8][4] = {};

#define STAGE_A(dd, kt) do {                                                   \
    __builtin_amdgcn_global_load_lds(                                          \
        (const __attribute__((address_space(1))) void*)(gA + (long)(kt)*32),   \
        (__attribute__((address_space(3))) void*)(&As[dd][ldst]), 16, 0, 0);   \
    __builtin_amdgcn_global_load_lds(                                          \
        (const __attribute__((address_space(1))) void*)(gA + (long)128*lda + (long)(kt)*32), \
        (__attribute__((address_space(3))) void*)(&As[dd][4096 + ldst]), 16, 0, 0);          \
} while (0)

#define STAGE_B(dd, kt) do {                                                   \
    __builtin_amdgcn_global_load_lds(                                          \
        (const __attribute__((address_space(1))) void*)(gB + (long)(kt)*32),   \
        (__attribute__((address_space(3))) void*)(&Bs[dd][ldst]), 16, 0, 0);   \
    __builtin_amdgcn_global_load_lds(                                          \
        (const __attribute__((address_space(1))) void*)(gB + (long)128*ldb + (long)(kt)*32), \
        (__attribute__((address_space(3))) void*)(&Bs[dd][4096 + ldst]), 16, 0, 0);          \
} while (0)

#define RD_A(dd) do {                                                          \
    _Pragma("unroll") for (int mr_ = 0; mr_ < 8; ++mr_)                        \
        aQ[mr_] = *(const short8*)&As[dd][arb + mr_ * 512 + pk];               \
} while (0)

#define RD_B(dd, nh) do {                                                      \
    bQ[(nh)*2 + 0] = *(const short8*)&Bs[dd][brb + ((nh)*2 + 0) * 512 + pk];   \
    bQ[(nh)*2 + 1] = *(const short8*)&Bs[dd][brb + ((nh)*2 + 1) * 512 + pk];   \
} while (0)

#define BARX __builtin_amdgcn_s_barrier()
#define WAIT_LGKM0 do { asm volatile("s_waitcnt lgkmcnt(0)" ::: "memory"); \
                        __builtin_amdgcn_sched_barrier(0); } while (0)
#define WAIT_VM0   do { asm volatile("s_waitcnt vmcnt(0)"   ::: "memory"); \
                        __builtin_amdgcn_sched_barrier(0); } while (0)
#define WAIT_VM2   do { asm volatile("s_waitcnt vmcnt(2)"   ::: "memory"); \
                        __builtin_amdgcn_sched_barrier(0); } while (0)

#define MFMA_PH(nh) do {                                                       \
    __builtin_amdgcn_s_setprio(1);                                             \
    _Pragma("unroll") for (int mr_ = 0; mr_ < 8; ++mr_)                        \
    _Pragma("unroll") for (int nr_ = 0; nr_ < 2; ++nr_)                        \
        acc[mr_][(nh)*2 + nr_] = __builtin_amdgcn_mfma_f32_16x16x32_bf16(      \
            aQ[mr_], bQ[(nh)*2 + nr_], acc[mr_][(nh)*2 + nr_], 0, 0, 0);       \
    __builtin_amdgcn_s_setprio(0);                                             \
} while (0)

#define TILE_STEP(d, kt) do {                                                  \
    /* P1 */                                                                   \
    RD_A(d); RD_B(d, 0);                                                       \
    if ((kt) + 1 < NT) STAGE_B((d) ^ 1, (kt) + 1);                             \
    BARX; WAIT_LGKM0; MFMA_PH(0); BARX;                                        \
    /* P2 */                                                                   \
    RD_B(d, 1);                                                                \
    if ((kt) + 2 < NT) { STAGE_A(d, (kt) + 2); WAIT_VM2; } else { WAIT_VM0; }  \
    BARX; WAIT_LGKM0; MFMA_PH(1); BARX;                                        \
} while (0)

    // prologue: T0 A+B -> dbuf0, T1 A -> dbuf1; drain T0, keep T1.A in flight.
    STAGE_A(0, 0); STAGE_B(0, 0); STAGE_A(1, 1);
    WAIT_VM2; BARX;

    for (int kt = 0; kt < NT; kt += 2) {
        TILE_STEP(0, kt);
        TILE_STEP(1, kt + 1);
    }

#undef STAGE_A
#undef STAGE_B
#undef RD_A
#undef RD_B
#undef BARX
#undef WAIT_LGKM0
#undef WAIT_VM0
#undef WAIT_VM2
#undef MFMA_PH
#undef TILE_STEP

    // epilogue: C/D layout col = lane&15 (=r), row = (lane>>4)*4 + reg (=q*4+rr)
    const int rbase = m0 + wr * 128;
    const int cbase = n0 + wc * 64;
    if (OUT_MODE == 1) {
        unsigned short* C = (unsigned short*)Cout + (long)b * strideC;
#pragma unroll
        for (int mt = 0; mt < 8; ++mt)
#pragma unroll
            for (int nt = 0; nt < 4; ++nt)
#pragma unroll
                for (int rr = 0; rr < 4; ++rr) {
                    const int grow = rbase + mt * 16 + q * 4 + rr;
                    const int gcol = cbase + nt * 16 + r;
                    C[(long)grow * ldc + gcol] = f2bf(acc[mt][nt][rr]);
                }
    } else if (OUT_MODE == 0) {
        float* C = (float*)Cout + (long)b * strideC;
#pragma unroll
        for (int mt = 0; mt < 8; ++mt)
#pragma unroll
            for (int nt = 0; nt < 4; ++nt)
#pragma unroll
                for (int rr = 0; rr < 4; ++rr) {
                    const int grow = rbase + mt * 16 + q * 4 + rr;
                    const int gcol = cbase + nt * 16 + r;
                    C[(long)grow * ldc + gcol] = acc[mt][nt][rr];
                }
    } else {
        float* C = (float*)Cout + (long)b * strideC;
#pragma unroll
        for (int mt = 0; mt < 8; ++mt)
#pragma unroll
            for (int nt = 0; nt < 4; ++nt)
#pragma unroll
                for (int rr = 0; rr < 4; ++rr) {
                    const int grow = rbase + mt * 16 + q * 4 + rr;
                    const int gcol = cbase + nt * 16 + r;
                    const float val = (grow < Lb && gcol < Lb) ? acc[mt][nt][rr] : NEGV;
                    C[(long)grow * ldc + gcol] = val;
                }
    }
}

// ---------------------------------------------------------------------------
// In-place row softmax over last dim (N_=2048). One block per row.
// Rows >= Lb are fully masked -> softmax is exactly 1/2048: write const,
// no read (also lets the logits GEMM skip those tiles entirely).
// ---------------------------------------------------------------------------
__global__ __launch_bounds__(256)
void softmax_rows(float* __restrict__ Att, const int* __restrict__ Lp)
{
    const size_t row = blockIdx.x;
    const int i = (int)(row & (N_ - 1));
    const int b = (int)(row >> 11);
    float* p = Att + row * (size_t)N_;
    const int t = threadIdx.x;

    if (i >= Lp[b]) {
        const float c = 1.0f / 2048.0f;
        const float4 cv = make_float4(c, c, c, c);
        *(float4*)(p + t * 4)        = cv;
        *(float4*)(p + 1024 + t * 4) = cv;
        return;
    }

    float4 v0 = *(float4*)(p + t * 4);
    float4 v1 = *(float4*)(p + 1024 + t * 4);

    float mx = fmaxf(fmaxf(fmaxf(v0.x, v0.y), fmaxf(v0.z, v0.w)),
                     fmaxf(fmaxf(v1.x, v1.y), fmaxf(v1.z, v1.w)));
#pragma unroll
    for (int o = 32; o > 0; o >>= 1) mx = fmaxf(mx, __shfl_xor(mx, o, 64));

    __shared__ float red[8];
    const int wv = t >> 6;
    if ((t & 63) == 0) red[wv] = mx;
    __syncthreads();
    mx = fmaxf(fmaxf(red[0], red[1]), fmaxf(red[2], red[3]));

    float e[8];
    e[0] = expf(v0.x - mx); e[1] = expf(v0.y - mx);
    e[2] = expf(v0.z - mx); e[3] = expf(v0.w - mx);
    e[4] = expf(v1.x - mx); e[5] = expf(v1.y - mx);
    e[6] = expf(v1.z - mx); e[7] = expf(v1.w - mx);
    float s = ((e[0] + e[1]) + (e[2] + e[3])) + ((e[4] + e[5]) + (e[6] + e[7]));
#pragma unroll
    for (int o = 32; o > 0; o >>= 1) s += __shfl_xor(s, o, 64);
    if ((t & 63) == 0) red[4 + wv] = s;
    __syncthreads();
    const float inv = 1.0f / (red[4] + red[5] + red[6] + red[7]);

    *(float4*)(p + t * 4)        = make_float4(e[0] * inv, e[1] * inv, e[2] * inv, e[3] * inv);
    *(float4*)(p + 1024 + t * 4) = make_float4(e[4] * inv, e[5] * inv, e[6] * inv, e[7] * inv);
}

// ---------------------------------------------------------------------------
// att f32 [b][j][i] -> attT bf16 [b][i][j], 64x64 LDS tile transpose.
// ---------------------------------------------------------------------------
__global__ __launch_bounds__(256)
void transpose_att_bf16(const float* __restrict__ att, unsigned short* __restrict__ attT)
{
    __shared__ float tile[64][65];
    const int b  = blockIdx.z;
    const int j0 = blockIdx.y * 64;
    const int i0 = blockIdx.x * 64;
    const float* src = att + (long)b * N_ * N_;
    unsigned short* dst = attT + (long)b * N_ * N_;
    const int t = threadIdx.x;
#pragma unroll
    for (int l = 0; l < 4; ++l) {
        const int idx = t + l * 256;
        const int jj = idx >> 4;
        const int i4 = (idx & 15) * 4;
        const float4 v = *(const float4*)(src + (long)(j0 + jj) * N_ + i0 + i4);
        tile[i4 + 0][jj] = v.x;
        tile[i4 + 1][jj] = v.y;
        tile[i4 + 2][jj] = v.z;
        tile[i4 + 3][jj] = v.w;
    }
    __syncthreads();
#pragma unroll
    for (int l = 0; l < 4; ++l) {
        const int idx = t + l * 256;
        const int ii = idx >> 4;
        const int j4 = (idx & 15) * 4;
        ushort4 o;
        o.x = f2bf(tile[ii][j4 + 0]);
        o.y = f2bf(tile[ii][j4 + 1]);
        o.z = f2bf(tile[ii][j4 + 2]);
        o.w = f2bf(tile[ii][j4 + 3]);
        *(ushort4*)(dst + (long)(i0 + ii) * N_ + j0 + j4) = o;
    }
}

// ---------------------------------------------------------------------------
// V slice of QKV [16384 tokens][3072] (cols 2048..3071) -> VT bf16 [1024][16384]
// ---------------------------------------------------------------------------
__global__ __launch_bounds__(256)
void transpose_v_bf16(const unsigned short* __restrict__ qkv, unsigned short* __restrict__ vt)
{
    __shared__ unsigned short tile[64][68];
    const int j0 = blockIdx.x * 64;
    const int d0 = blockIdx.y * 64;
    const int t = threadIdx.x;
#pragma unroll
    for (int l = 0; l < 4; ++l) {
        const int idx = t + l * 256;
        const int jj = idx >> 4;
        const int d4 = (idx & 15) * 4;
        const ushort4 v = *(const ushort4*)(qkv + (long)(j0 + jj) * 3072 + 2048 + d0 + d4);
        tile[d4 + 0][jj] = v.x;
        tile[d4 + 1][jj] = v.y;
        tile[d4 + 2][jj] = v.z;
        tile[d4 + 3][jj] = v.w;
    }
    __syncthreads();
#pragma unroll
    for (int l = 0; l < 4; ++l) {
        const int idx = t + l * 256;
        const int dd = idx >> 4;
        const int j4 = (idx & 15) * 4;
        ushort4 o;
        o.x = tile[dd][j4 + 0];
        o.y = tile[dd][j4 + 1];
        o.z = tile[dd][j4 + 2];
        o.w = tile[dd][j4 + 3];
        *(ushort4*)(vt + (long)(d0 + dd) * 16384 + j0 + j4) = o;
    }
}

// ---------------------------------------------------------------------------
extern "C" void kernel_launch(void* const* d_in, const int* in_sizes, int n_in,
                              void* d_out, int out_size, void* d_ws, size_t ws_size,
                              hipStream_t stream)
{
    const float* x  = (const float*)d_in[0];
    const unsigned char* mask = (const unsigned char*)d_in[1];
    const float* Wq = (const float*)d_in[2];
    const float* Wk = (const float*)d_in[3];
    const float* Wv = (const float*)d_in[4];
    const float* Wo = (const float*)d_in[5];

    float* y   = (float*)d_out;                          // [B,N,D] f32
    float* att = (float*)d_out + (size_t)B_ * N_ * D_;   // [B,N,N] f32

    char* ws = (char*)d_ws;
    int* L = (int*)ws;
    unsigned short* Wqkvb = (unsigned short*)(ws + 256); // [3072,1024] (Q|K|V rows)
    unsigned short* Wob   = Wqkvb + 3145728;             // [1024,1024]
    unsigned short* xb    = Wob + 1048576;               // [16384,1024]
    unsigned short* QKVb  = xb + 16777216;               // [16384,3072]
    unsigned short* VT    = QKVb + 50331648;             // [1024,16384]
    unsigned short* attT  = QKVb;                        // [B,N,N] bf16 (reuses QKV)
    unsigned short* ctx   = xb;                          // [16384,1024] bf16 (reuses xb)

    const dim3 blk(256);
    const dim3 blk512(512);
    const long NN = (long)N_ * N_;
    const long ND = (long)N_ * D_;
    const long NQ = (long)N_ * 3072;

    k_lengths<<<dim3(B_), blk, 0, stream>>>(mask, L);

    convert_bf16<<<dim3(16384), blk, 0, stream>>>(x,  xb,  4194304, 1.0f);
    convert_bf16<<<dim3(1024),  blk, 0, stream>>>(Wq, Wqkvb,           262144, 0.06f);
    convert_bf16<<<dim3(1024),  blk, 0, stream>>>(Wk, Wqkvb + 1048576, 262144, 1.0f);
    convert_bf16<<<dim3(1024),  blk, 0, stream>>>(Wv, Wqkvb + 2097152, 262144, 1.0f);
    convert_bf16<<<dim3(1024),  blk, 0, stream>>>(Wo, Wob,             262144, 1.0f);

    // Fused QKV = x @ [Wq*0.06 | Wk | Wv]^T -> [16384, 3072] bf16
    gemm_nt_256<1><<<dim3(12, 64, 1), blk512, 0, stream>>>(
        xb, D_, 0, Wqkvb, D_, 0, QKVb, 3072, 0, D_, nullptr);

    // VT[d][b*N+j] = V[b*N+j][d]
    transpose_v_bf16<<<dim3(256, 16), blk, 0, stream>>>(QKVb, VT);

    // logits = Q K^T with prefix mask (f32 out into att region)
    gemm_nt_256<2><<<dim3(8, 8, B_), blk512, 0, stream>>>(
        QKVb, 3072, NQ, QKVb + 1024, 3072, NQ, att, N_, NN, D_, L);

    softmax_rows<<<dim3(B_ * N_), blk, 0, stream>>>(att, L);

    // attT bf16 (reuses QKV space; Q/K/V all consumed by now)
    transpose_att_bf16<<<dim3(32, 32, B_), blk, 0, stream>>>(att, attT);

    // ctx[b][i][d] = sum_j attT[b][i][j] * VT[d][b*N + j]
    gemm_nt_256<1><<<dim3(4, 8, B_), blk512, 0, stream>>>(
        attT, N_, NN, VT, B_ * N_, N_, ctx, D_, ND, N_, nullptr);

    // y = ctx Wo^T (f32 out)
    gemm_nt_256<0><<<dim3(4, 64, 1), blk512, 0, stream>>>(
        ctx, D_, 0, Wob, D_, 0, y, D_, 0, D_, nullptr);
}

// Round 5
// 619.379 us; speedup vs baseline: 1.3104x; 1.0224x over previous
//
#include <hip/hip_runtime.h>
#include <math.h>

typedef __attribute__((ext_vector_type(8))) short short8;
typedef __attribute__((ext_vector_type(4))) float f32x4;

namespace {
constexpr int B_ = 8;
constexpr int N_ = 2048;
constexpr int D_ = 1024;
constexpr float NEGV = -1.0e9f;
}

__device__ __forceinline__ unsigned short f2bf(float x) {
    union { float f; unsigned u; } v; v.f = x;
    unsigned u = v.u + 0x7fffu + ((v.u >> 16) & 1u);
    return (unsigned short)(u >> 16);
}

// ---------------------------------------------------------------------------
// Per-batch valid lengths from the prefix mask (uint8 or int32 layout).
// ---------------------------------------------------------------------------
__global__ __launch_bounds__(256)
void k_lengths(const unsigned char* __restrict__ mask, int* __restrict__ L)
{
    const int b = blockIdx.x;
    const int t = threadIdx.x;
    const bool u8 = (mask[1] != 0);
    int cnt = 0;
    if (u8) {
        for (int n = t; n < N_; n += 256)
            cnt += (mask[(size_t)b * N_ + n] != 0) ? 1 : 0;
    } else {
        const int* mi = (const int*)mask;
        for (int n = t; n < N_; n += 256)
            cnt += (mi[(size_t)b * N_ + n] != 0) ? 1 : 0;
    }
    __shared__ int red[256];
    red[t] = cnt;
    __syncthreads();
    for (int s = 128; s > 0; s >>= 1) {
        if (t < s) red[t] += red[t + s];
        __syncthreads();
    }
    if (t == 0) L[b] = red[0];
}

// ---------------------------------------------------------------------------
// f32 -> bf16 conversion (with optional scale), 1 float4 per thread.
// ---------------------------------------------------------------------------
__global__ __launch_bounds__(256)
void convert_bf16(const float* __restrict__ in, unsigned short* __restrict__ out,
                  int n4, float alpha)
{
    const int i = blockIdx.x * 256 + threadIdx.x;
    if (i >= n4) return;
    const float4 v = ((const float4*)in)[i];
    ushort4 o;
    o.x = f2bf(v.x * alpha); o.y = f2bf(v.y * alpha);
    o.z = f2bf(v.z * alpha); o.w = f2bf(v.w * alpha);
    ((ushort4*)out)[i] = o;
}

// ---------------------------------------------------------------------------
// 256x256 deep-pipelined bf16 NT-GEMM (C[m][n] = sum_k A[m][k]*B[n][k]).
//
// 512 threads = 8 waves (2 Mrow x 4 Ncol), per-wave 128x64 output,
// 16x16x32 MFMA, BK=32, 4-deep LDS buffering (128 KiB), counted vmcnt.
//
// ROUND-5: round 4 was latency-bound (MfmaUtil 35%, VALUBusy 17%, HBM 20%):
// prefetch distance was 1 phase vs ~900cy HBM latency, and occupancy is
// register-capped at 1 block/CU (acc=128 AGPR) so no TLP covers the stall.
// Fix: 4-deep buffers (LDS was free), stage tile T+3 during tile T; the
// per-tile wait becomes vmcnt(8) (tiles T+2,T+3 in flight), issue-to-use
// slack ~6 phases. Phases rebalanced by m-half (frag liveness 32 VGPR).
//
// LDS rows are 64 B (4 x 16B segs). Seg swizzle: phys = logical ^ ((row>>1)&3)
// -> quarter-wave ds_read_b128 lands 2-way on banks (free, m136). Staging
// pre-swizzles the GLOBAL source seg; LDS dest stays linear (gload_lds rule).
//
// Per K-tile T (buf d=T&3), 2 phases:
//  P1: dsread a0-3 + b0-3 (8) | stage (T+3).B -> (T+3)&3
//      | BAR lgkm0 MFMA(m0-3 x n0-3) BAR
//  P2: dsread a4-7 (4)        | stage (T+3).A -> (T+3)&3 + vmcnt(8)
//      | BAR lgkm0 MFMA(m4-7 x n0-3) BAR
// Ledger at P2 wait (4 loads/tile, B-then-A order): outstanding =
// B/A(T+2), B/A(T+3) = 8 after draining through A(T+1) -> vmcnt(8) makes
// tile T+1 fully resident before the barrier preceding its P1 reads.
// Tails: kt+3>=NT -> no stage, vmcnt(4); kt+2>=NT -> vmcnt(0).
// WAR: buffer (T+3)&3 last read in tile T-1, sealed by its final barrier,
// which precedes every stage issue for T+3 (P1/P2 of T). Requires NT>=3
// (all launches: NT in {32,64}).
//
// OUT_MODE: 0 = f32, 1 = bf16, 2 = f32 with prefix mask (logits):
//   m0 >= Lb -> return with NO writes (softmax writes those rows whole);
//   n0 >= Lb -> NEGV fill, no compute.
// XCD swizzle: bijective chunking, n-fastest within chunk (B-panel L2-hot).
// ---------------------------------------------------------------------------
template <int OUT_MODE>
__global__ __launch_bounds__(512, 2)
void gemm_nt_256(const unsigned short* __restrict__ A, int lda, long strideA,
                 const unsigned short* __restrict__ Bm, int ldb, long strideB,
                 void* __restrict__ Cout, int ldc, long strideC,
                 int K, const int* __restrict__ Lp)
{
    __shared__ __attribute__((aligned(16))) short As[4][8192];
    __shared__ __attribute__((aligned(16))) short Bs[4][8192];

    const int tid  = threadIdx.x;
    const int lane = tid & 63;
    const int wave = tid >> 6;
    const int wr   = wave >> 2;   // 0..1
    const int wc   = wave & 3;    // 0..3

    // ---- XCD-aware bijective block swizzle (n-fastest within chunk) ----
    const unsigned gx   = gridDim.x;
    const unsigned gxy  = gx * gridDim.y;
    const unsigned total = gxy * gridDim.z;
    const unsigned orig = blockIdx.x + gx * blockIdx.y + gxy * blockIdx.z;
    unsigned wg = orig;
    if ((total & 7u) == 0u)
        wg = (orig & 7u) * (total >> 3) + (orig >> 3);
    const unsigned bz  = wg / gxy;
    const unsigned rem = wg - bz * gxy;
    const unsigned byy = rem / gx;
    const unsigned bxx = rem - byy * gx;

    const int b  = (int)bz;
    const int m0 = (int)byy * 256;
    const int n0 = (int)bxx * 256;

    int Lb = 0;
    if (OUT_MODE == 2) {
        Lb = Lp[b];
        if (m0 >= Lb) return;   // softmax writes these rows entirely (const)
        if (n0 >= Lb) {
            // masked columns of valid rows: NEGV fill, no compute
            float* C = (float*)Cout + (long)b * strideC;
            const float4 nv = make_float4(NEGV, NEGV, NEGV, NEGV);
            const int rl = tid >> 6;          // 0..7
            const int c4 = (tid & 63) * 4;    // 0..252
#pragma unroll
            for (int l = 0; l < 32; ++l)
                *(float4*)(C + (long)(m0 + l * 8 + rl) * ldc + n0 + c4) = nv;
            return;
        }
    }

    const unsigned short* Ab = A  + (long)b * strideA;
    const unsigned short* Bb = Bm + (long)b * strideB;

    // staging: one STAGE (2 gload_lds/wave) covers 128 rows x 64 B.
    // chunk = tid: row = tid>>2, phys seg = tid&3; pre-swizzled global seg:
    const int srow = tid >> 2;                               // 0..127
    const int sseg = ((tid & 3) ^ ((tid >> 3) & 3)) * 8;     // shorts
    const unsigned short* gA = Ab + (long)(m0 + srow) * lda + sseg;
    const unsigned short* gB = Bb + (long)(n0 + srow) * ldb + sseg;
    const int ldst = (tid & ~63) * 8;   // wave-uniform LDS chunk base (shorts)

    // fragment reads: row = base + r, phys seg = q ^ ((r>>1)&3)
    const int q  = lane >> 4, r = lane & 15;
    const int arb = (wr * 128 + r) * 32;
    const int brb = (wc * 64 + r) * 32;
    const int pk  = (q ^ ((r >> 1) & 3)) * 8;

    const int NT = K >> 5;   // K-tiles of 32 (NT in {32,64} here)

    short8 aH[4];
    short8 bQ[4];
    f32x4  acc[8][4] = {};

#define STAGE_A(dd, kt) do {                                                   \
    __builtin_amdgcn_global_load_lds(                                          \
        (const __attribute__((address_space(1))) void*)(gA + (long)(kt)*32),   \
        (__attribute__((address_space(3))) void*)(&As[dd][ldst]), 16, 0, 0);   \
    __builtin_amdgcn_global_load_lds(                                          \
        (const __attribute__((address_space(1))) void*)(gA + (long)128*lda + (long)(kt)*32), \
        (__attribute__((address_space(3))) void*)(&As[dd][4096 + ldst]), 16, 0, 0);          \
} while (0)

#define STAGE_B(dd, kt) do {                                                   \
    __builtin_amdgcn_global_load_lds(                                          \
        (const __attribute__((address_space(1))) void*)(gB + (long)(kt)*32),   \
        (__attribute__((address_space(3))) void*)(&Bs[dd][ldst]), 16, 0, 0);   \
    __builtin_amdgcn_global_load_lds(                                          \
        (const __attribute__((address_space(1))) void*)(gB + (long)128*ldb + (long)(kt)*32), \
        (__attribute__((address_space(3))) void*)(&Bs[dd][4096 + ldst]), 16, 0, 0);          \
} while (0)

#define RD_A_H(dd, mh) do {                                                    \
    _Pragma("unroll") for (int mr_ = 0; mr_ < 4; ++mr_)                        \
        aH[mr_] = *(const short8*)&As[dd][arb + ((mh)*4 + mr_) * 512 + pk];    \
} while (0)

#define RD_B_ALL(dd) do {                                                      \
    _Pragma("unroll") for (int nr_ = 0; nr_ < 4; ++nr_)                        \
        bQ[nr_] = *(const short8*)&Bs[dd][brb + nr_ * 512 + pk];               \
} while (0)

#define BARX __builtin_amdgcn_s_barrier()
#define WAIT_LGKM0 do { asm volatile("s_waitcnt lgkmcnt(0)" ::: "memory"); \
                        __builtin_amdgcn_sched_barrier(0); } while (0)
#define WAIT_VM0   do { asm volatile("s_waitcnt vmcnt(0)"   ::: "memory"); \
                        __builtin_amdgcn_sched_barrier(0); } while (0)
#define WAIT_VM4   do { asm volatile("s_waitcnt vmcnt(4)"   ::: "memory"); \
                        __builtin_amdgcn_sched_barrier(0); } while (0)
#define WAIT_VM8   do { asm volatile("s_waitcnt vmcnt(8)"   ::: "memory"); \
                        __builtin_amdgcn_sched_barrier(0); } while (0)

#define MFMA_H(mh) do {                                                        \
    __builtin_amdgcn_s_setprio(1);                                             \
    _Pragma("unroll") for (int mr_ = 0; mr_ < 4; ++mr_)                        \
    _Pragma("unroll") for (int nr_ = 0; nr_ < 4; ++nr_)                        \
        acc[(mh)*4 + mr_][nr_] = __builtin_amdgcn_mfma_f32_16x16x32_bf16(      \
            aH[mr_], bQ[nr_], acc[(mh)*4 + mr_][nr_], 0, 0, 0);                \
    __builtin_amdgcn_s_setprio(0);                                             \
} while (0)

    // prologue: stage tiles 0,1,2 (B then A each); drain tile 0, keep 8 in flight.
    STAGE_B(0, 0); STAGE_A(0, 0);
    STAGE_B(1, 1); STAGE_A(1, 1);
    STAGE_B(2, 2); STAGE_A(2, 2);
    WAIT_VM8; BARX;

    for (int kt = 0; kt < NT; ++kt) {
        const int d  = kt & 3;
        const int dn = (kt + 3) & 3;
        // P1
        RD_A_H(d, 0); RD_B_ALL(d);
        if (kt + 3 < NT) STAGE_B(dn, kt + 3);
        BARX; WAIT_LGKM0; MFMA_H(0); BARX;
        // P2
        RD_A_H(d, 1);
        if (kt + 3 < NT) { STAGE_A(dn, kt + 3); WAIT_VM8; }
        else if (kt + 2 < NT) { WAIT_VM4; }
        else { WAIT_VM0; }
        BARX; WAIT_LGKM0; MFMA_H(1); BARX;
    }

#undef STAGE_A
#undef STAGE_B
#undef RD_A_H
#undef RD_B_ALL
#undef BARX
#undef WAIT_LGKM0
#undef WAIT_VM0
#undef WAIT_VM4
#undef WAIT_VM8
#undef MFMA_H

    // epilogue: C/D layout col = lane&15 (=r), row = (lane>>4)*4 + reg (=q*4+rr)
    const int rbase = m0 + wr * 128;
    const int cbase = n0 + wc * 64;
    if (OUT_MODE == 1) {
        unsigned short* C = (unsigned short*)Cout + (long)b * strideC;
#pragma unroll
        for (int mt = 0; mt < 8; ++mt)
#pragma unroll
            for (int nt = 0; nt < 4; ++nt)
#pragma unroll
                for (int rr = 0; rr < 4; ++rr) {
                    const int grow = rbase + mt * 16 + q * 4 + rr;
                    const int gcol = cbase + nt * 16 + r;
                    C[(long)grow * ldc + gcol] = f2bf(acc[mt][nt][rr]);
                }
    } else if (OUT_MODE == 0) {
        float* C = (float*)Cout + (long)b * strideC;
#pragma unroll
        for (int mt = 0; mt < 8; ++mt)
#pragma unroll
            for (int nt = 0; nt < 4; ++nt)
#pragma unroll
                for (int rr = 0; rr < 4; ++rr) {
                    const int grow = rbase + mt * 16 + q * 4 + rr;
                    const int gcol = cbase + nt * 16 + r;
                    C[(long)grow * ldc + gcol] = acc[mt][nt][rr];
                }
    } else {
        float* C = (float*)Cout + (long)b * strideC;
#pragma unroll
        for (int mt = 0; mt < 8; ++mt)
#pragma unroll
            for (int nt = 0; nt < 4; ++nt)
#pragma unroll
                for (int rr = 0; rr < 4; ++rr) {
                    const int grow = rbase + mt * 16 + q * 4 + rr;
                    const int gcol = cbase + nt * 16 + r;
                    const float val = (grow < Lb && gcol < Lb) ? acc[mt][nt][rr] : NEGV;
                    C[(long)grow * ldc + gcol] = val;
                }
    }
}

// ---------------------------------------------------------------------------
// In-place row softmax over last dim (N_=2048). One block per row.
// Rows >= Lb are fully masked -> softmax is exactly 1/2048: write const,
// no read (also lets the logits GEMM skip those tiles entirely).
// ---------------------------------------------------------------------------
__global__ __launch_bounds__(256)
void softmax_rows(float* __restrict__ Att, const int* __restrict__ Lp)
{
    const size_t row = blockIdx.x;
    const int i = (int)(row & (N_ - 1));
    const int b = (int)(row >> 11);
    float* p = Att + row * (size_t)N_;
    const int t = threadIdx.x;

    if (i >= Lp[b]) {
        const float c = 1.0f / 2048.0f;
        const float4 cv = make_float4(c, c, c, c);
        *(float4*)(p + t * 4)        = cv;
        *(float4*)(p + 1024 + t * 4) = cv;
        return;
    }

    float4 v0 = *(float4*)(p + t * 4);
    float4 v1 = *(float4*)(p + 1024 + t * 4);

    float mx = fmaxf(fmaxf(fmaxf(v0.x, v0.y), fmaxf(v0.z, v0.w)),
                     fmaxf(fmaxf(v1.x, v1.y), fmaxf(v1.z, v1.w)));
#pragma unroll
    for (int o = 32; o > 0; o >>= 1) mx = fmaxf(mx, __shfl_xor(mx, o, 64));

    __shared__ float red[8];
    const int wv = t >> 6;
    if ((t & 63) == 0) red[wv] = mx;
    __syncthreads();
    mx = fmaxf(fmaxf(red[0], red[1]), fmaxf(red[2], red[3]));

    float e[8];
    e[0] = expf(v0.x - mx); e[1] = expf(v0.y - mx);
    e[2] = expf(v0.z - mx); e[3] = expf(v0.w - mx);
    e[4] = expf(v1.x - mx); e[5] = expf(v1.y - mx);
    e[6] = expf(v1.z - mx); e[7] = expf(v1.w - mx);
    float s = ((e[0] + e[1]) + (e[2] + e[3])) + ((e[4] + e[5]) + (e[6] + e[7]));
#pragma unroll
    for (int o = 32; o > 0; o >>= 1) s += __shfl_xor(s, o, 64);
    if ((t & 63) == 0) red[4 + wv] = s;
    __syncthreads();
    const float inv = 1.0f / (red[4] + red[5] + red[6] + red[7]);

    *(float4*)(p + t * 4)        = make_float4(e[0] * inv, e[1] * inv, e[2] * inv, e[3] * inv);
    *(float4*)(p + 1024 + t * 4) = make_float4(e[4] * inv, e[5] * inv, e[6] * inv, e[7] * inv);
}

// ---------------------------------------------------------------------------
// att f32 [b][j][i] -> attT bf16 [b][i][j], 64x64 LDS tile transpose.
// ---------------------------------------------------------------------------
__global__ __launch_bounds__(256)
void transpose_att_bf16(const float* __restrict__ att, unsigned short* __restrict__ attT)
{
    __shared__ float tile[64][65];
    const int b  = blockIdx.z;
    const int j0 = blockIdx.y * 64;
    const int i0 = blockIdx.x * 64;
    const float* src = att + (long)b * N_ * N_;
    unsigned short* dst = attT + (long)b * N_ * N_;
    const int t = threadIdx.x;
#pragma unroll
    for (int l = 0; l < 4; ++l) {
        const int idx = t + l * 256;
        const int jj = idx >> 4;
        const int i4 = (idx & 15) * 4;
        const float4 v = *(const float4*)(src + (long)(j0 + jj) * N_ + i0 + i4);
        tile[i4 + 0][jj] = v.x;
        tile[i4 + 1][jj] = v.y;
        tile[i4 + 2][jj] = v.z;
        tile[i4 + 3][jj] = v.w;
    }
    __syncthreads();
#pragma unroll
    for (int l = 0; l < 4; ++l) {
        const int idx = t + l * 256;
        const int ii = idx >> 4;
        const int j4 = (idx & 15) * 4;
        ushort4 o;
        o.x = f2bf(tile[ii][j4 + 0]);
        o.y = f2bf(tile[ii][j4 + 1]);
        o.z = f2bf(tile[ii][j4 + 2]);
        o.w = f2bf(tile[ii][j4 + 3]);
        *(ushort4*)(dst + (long)(i0 + ii) * N_ + j0 + j4) = o;
    }
}

// ---------------------------------------------------------------------------
// V slice of QKV [16384 tokens][3072] (cols 2048..3071) -> VT bf16 [1024][16384]
// ---------------------------------------------------------------------------
__global__ __launch_bounds__(256)
void transpose_v_bf16(const unsigned short* __restrict__ qkv, unsigned short* __restrict__ vt)
{
    __shared__ unsigned short tile[64][68];
    const int j0 = blockIdx.x * 64;
    const int d0 = blockIdx.y * 64;
    const int t = threadIdx.x;
#pragma unroll
    for (int l = 0; l < 4; ++l) {
        const int idx = t + l * 256;
        const int jj = idx >> 4;
        const int d4 = (idx & 15) * 4;
        const ushort4 v = *(const ushort4*)(qkv + (long)(j0 + jj) * 3072 + 2048 + d0 + d4);
        tile[d4 + 0][jj] = v.x;
        tile[d4 + 1][jj] = v.y;
        tile[d4 + 2][jj] = v.z;
        tile[d4 + 3][jj] = v.w;
    }
    __syncthreads();
#pragma unroll
    for (int l = 0; l < 4; ++l) {
        const int idx = t + l * 256;
        const int dd = idx >> 4;
        const int j4 = (idx & 15) * 4;
        ushort4 o;
        o.x = tile[dd][j4 + 0];
        o.y = tile[dd][j4 + 1];
        o.z = tile[dd][j4 + 2];
        o.w = tile[dd][j4 + 3];
        *(ushort4*)(vt + (long)(d0 + dd) * 16384 + j0 + j4) = o;
    }
}

// ---------------------------------------------------------------------------
extern "C" void kernel_launch(void* const* d_in, const int* in_sizes, int n_in,
                              void* d_out, int out_size, void* d_ws, size_t ws_size,
                              hipStream_t stream)
{
    const float* x  = (const float*)d_in[0];
    const unsigned char* mask = (const unsigned char*)d_in[1];
    const float* Wq = (const float*)d_in[2];
    const float* Wk = (const float*)d_in[3];
    const float* Wv = (const float*)d_in[4];
    const float* Wo = (const float*)d_in[5];

    float* y   = (float*)d_out;                          // [B,N,D] f32
    float* att = (float*)d_out + (size_t)B_ * N_ * D_;   // [B,N,N] f32

    char* ws = (char*)d_ws;
    int* L = (int*)ws;
    unsigned short* Wqkvb = (unsigned short*)(ws + 256); // [3072,1024] (Q|K|V rows)
    unsigned short* Wob   = Wqkvb + 3145728;             // [1024,1024]
    unsigned short* xb    = Wob + 1048576;               // [16384,1024]
    unsigned short* QKVb  = xb + 16777216;               // [16384,3072]
    unsigned short* VT    = QKVb + 50331648;             // [1024,16384]
    unsigned short* attT  = QKVb;                        // [B,N,N] bf16 (reuses QKV)
    unsigned short* ctx   = xb;                          // [16384,1024] bf16 (reuses xb)

    const dim3 blk(256);
    const dim3 blk512(512);
    const long NN = (long)N_ * N_;
    const long ND = (long)N_ * D_;
    const long NQ = (long)N_ * 3072;

    k_lengths<<<dim3(B_), blk, 0, stream>>>(mask, L);

    convert_bf16<<<dim3(16384), blk, 0, stream>>>(x,  xb,  4194304, 1.0f);
    convert_bf16<<<dim3(1024),  blk, 0, stream>>>(Wq, Wqkvb,           262144, 0.06f);
    convert_bf16<<<dim3(1024),  blk, 0, stream>>>(Wk, Wqkvb + 1048576, 262144, 1.0f);
    convert_bf16<<<dim3(1024),  blk, 0, stream>>>(Wv, Wqkvb + 2097152, 262144, 1.0f);
    convert_bf16<<<dim3(1024),  blk, 0, stream>>>(Wo, Wob,             262144, 1.0f);

    // Fused QKV = x @ [Wq*0.06 | Wk | Wv]^T -> [16384, 3072] bf16
    gemm_nt_256<1><<<dim3(12, 64, 1), blk512, 0, stream>>>(
        xb, D_, 0, Wqkvb, D_, 0, QKVb, 3072, 0, D_, nullptr);

    // VT[d][b*N+j] = V[b*N+j][d]
    transpose_v_bf16<<<dim3(256, 16), blk, 0, stream>>>(QKVb, VT);

    // logits = Q K^T with prefix mask (f32 out into att region)
    gemm_nt_256<2><<<dim3(8, 8, B_), blk512, 0, stream>>>(
        QKVb, 3072, NQ, QKVb + 1024, 3072, NQ, att, N_, NN, D_, L);

    softmax_rows<<<dim3(B_ * N_), blk, 0, stream>>>(att, L);

    // attT bf16 (reuses QKV space; Q/K/V all consumed by now)
    transpose_att_bf16<<<dim3(32, 32, B_), blk, 0, stream>>>(att, attT);

    // ctx[b][i][d] = sum_j attT[b][i][j] * VT[d][b*N + j]
    gemm_nt_256<1><<<dim3(4, 8, B_), blk512, 0, stream>>>(
        attT, N_, NN, VT, B_ * N_, N_, ctx, D_, ND, N_, nullptr);

    // y = ctx Wo^T (f32 out)
    gemm_nt_256<0><<<dim3(4, 64, 1), blk512, 0, stream>>>(
        ctx, D_, 0, Wob, D_, 0, y, D_, 0, D_, nullptr);
}